// Round 1
// baseline (433.728 us; speedup 1.0000x reference)
//
#include <hip/hip_runtime.h>
#include <hip/hip_cooperative_groups.h>

typedef unsigned int u32;
typedef __bf16 bf16x8 __attribute__((ext_vector_type(8)));
typedef float f32x4 __attribute__((ext_vector_type(4)));

#define B_DIM 4
#define E_DIM 200000
#define C_OUT 64
#define TPB   12500            // 16-edge tiles per batch
#define NT    (B_DIM * TPB)    // 50000 tiles
#define NBLK  1280             // fallback grid: 5 blocks/CU
#define ECH   782              // ceil(E_DIM/256) transpose chunks per batch
#define NCHUNK (B_DIM * ECH)   // 3128 transpose chunks
#define WLDS_U4 1792           // weight LDS: 7 chunks * 4 quads * 64 outs uint4

// round-half-up bf16 pack of two floats -> packed u32 (lo in low half).
// float is sign-magnitude, so +0x8000 on the bit pattern rounds the magnitude.
__device__ __forceinline__ u32 pack_bf2(float lo, float hi) {
  u32 a = __float_as_uint(lo) + 0x8000u;
  u32 b = __float_as_uint(hi) + 0x8000u;
  return __builtin_amdgcn_perm(b, a, 0x07060302u);  // [hi16(b) : hi16(a)]
}

// |bf16(a_i) - bf16(b_i)| for a packed pair, result packed bf16.
__device__ __forceinline__ u32 absdiff_pack(u32 a, u32 b) {
  float alo = __uint_as_float(a << 16), ahi = __uint_as_float(a & 0xffff0000u);
  float blo = __uint_as_float(b << 16), bhi = __uint_as_float(b & 0xffff0000u);
  u32 dlo = __float_as_uint(alo - blo) + 0x8000u;
  u32 dhi = __float_as_uint(ahi - bhi) + 0x8000u;
  return __builtin_amdgcn_perm(dhi, dlo, 0x07060302u) & 0x7fff7fffu;
}

__device__ __forceinline__ uint4 absdiff_vec(uint4 a, uint4 b) {
  return make_uint4(absdiff_pack(a.x, b.x), absdiff_pack(a.y, b.y),
                    absdiff_pack(a.z, b.z), absdiff_pack(a.w, b.w));
}

// ============================================================================
// Fused cooperative kernel:
//   phase 0: swizzle W -> LDS Wl (per block; kills prep_w + global round-trip)
//   phase 1: transpose x (B,C,E) f32 -> xT (B,E,16) packed bf16 (register-only,
//            no LDS tile so phase 2 keeps 28 KB / 5 blocks-per-CU occupancy)
//   grid.sync()
//   phase 2: MFMA mesh conv main loop (identical structure to mesh_main)
// ============================================================================
__global__ __launch_bounds__(256) void fused_mesh(
    const float* __restrict__ x, const int* __restrict__ Gi,
    const float* __restrict__ W, const float* __restrict__ bias,
    u32* __restrict__ xT, float* __restrict__ out, int nblk) {
  __shared__ uint4 Wl[WLDS_U4];  // 28 KB

  // ---- phase 0: build swizzled bf16 weights directly in LDS ----------------
  // Wl_flat[((s*4+q)*64 + o)*4 + r] = pack(W[o][q*8+2r][kk], W[o][q*8+2r+1][kk])
  // K-chunks s=0..6 multiply {f0, f1, f2, f3, f4, |f1-f3|, |f2-f4|}
  {
    u32* wl = (u32*)&Wl[0];
#pragma unroll
    for (int k = 0; k < 28; ++k) {
      const int p = (int)threadIdx.x + k * 256;  // < 7168
      const int r = p & 3;
      const int o = (p >> 2) & 63;
      const int q = (p >> 8) & 3;
      const int s = p >> 10;
      const int kk = s < 3 ? s : s - 2;          // {0,1,2,1,2,3,4}
      const int c0 = q * 8 + 2 * r;
      const float w0 = W[(o * 32 + c0) * 5 + kk];
      const float w1 = W[(o * 32 + c0 + 1) * 5 + kk];
      wl[p] = pack_bf2(w0, w1);
    }
  }

  // ---- phase 1: x -> xT, grid-stride over 256-edge chunks ------------------
  for (int cid = blockIdx.x; cid < NCHUNK; cid += nblk) {
    const int b = cid / ECH;
    const int e = (cid - b * ECH) * 256 + (int)threadIdx.x;
    if (e < E_DIM) {
      const float* xb = x + (size_t)b * 32 * E_DIM + e;
      uint4 row[4];
#pragma unroll
      for (int u = 0; u < 16; ++u) {
        const float lo = xb[(size_t)(2 * u) * E_DIM];      // coalesced per u
        const float hi = xb[(size_t)(2 * u + 1) * E_DIM];
        ((u32*)row)[u] = pack_bf2(lo, hi);
      }
      uint4* dst = (uint4*)(xT + ((size_t)b * E_DIM + e) * 16);  // own 64B row
#pragma unroll
      for (int k = 0; k < 4; ++k) dst[k] = row[k];
    }
  }

  // ---- phase 2 setup (independent of xT: hoist above the grid sync) --------
  const int l = (int)threadIdx.x & 63;
  const int wv = (int)threadIdx.x >> 6;
  const int n = l & 15;   // edge-in-tile == B-frag column
  const int q = l >> 4;   // quad == gather j4 == B-frag k-group
  const int NW = nblk * 4;

  f32x4 bv[4];
#pragma unroll
  for (int og = 0; og < 4; ++og) bv[og] = *(const f32x4*)(bias + og * 16 + q * 4);

  int t = blockIdx.x * 4 + wv;  // < nblk*4 <= 5120 < NT always

  int gcur[5], gnext[5];
  {
    const int b = t / TPB;
    const int e = (t - b * TPB) * 16 + n;
    const int* gp = Gi + (b * E_DIM + e) * 5;
#pragma unroll
    for (int s = 0; s < 5; ++s) gcur[s] = b * E_DIM + gp[s];
  }
  int t1 = t + NW;
  if (t1 < NT) {
    const int b = t1 / TPB;
    const int e = (t1 - b * TPB) * 16 + n;
    const int* gp = Gi + (b * E_DIM + e) * 5;
#pragma unroll
    for (int s = 0; s < 5; ++s) gnext[s] = b * E_DIM + gp[s];
  }

  // xT fully written; make it visible grid-wide
  cooperative_groups::this_grid().sync();

  const uint4* xb4 = (const uint4*)xT;
  uint4 cur[5];
#pragma unroll
  for (int s = 0; s < 5; ++s) cur[s] = xb4[(size_t)gcur[s] * 4 + q];

  for (;;) {
    const bool has = t1 < NT;  // wave-uniform
    // stage B: gather tile t1 (Gi already resident for >=1 iteration)
    uint4 nxt[5];
    if (has) {
#pragma unroll
      for (int s = 0; s < 5; ++s) nxt[s] = xb4[(size_t)gnext[s] * 4 + q];
    }
    // stage A: Gi for tile t1+NW
    const int t2 = t1 + NW;
    if (t2 < NT) {
      const int b = t2 / TPB;
      const int e = (t2 - b * TPB) * 16 + n;
      const int* gp = Gi + (b * E_DIM + e) * 5;
#pragma unroll
      for (int s = 0; s < 5; ++s) gnext[s] = b * E_DIM + gp[s];
    }

    // stage C: compute tile t
    union { uint4 u; bf16x8 v; } frag[7];
#pragma unroll
    for (int s = 0; s < 5; ++s) frag[s].u = cur[s];
    frag[5].u = absdiff_vec(cur[1], cur[3]);
    frag[6].u = absdiff_vec(cur[2], cur[4]);

    f32x4 acc0 = bv[0], acc1 = bv[1], acc2 = bv[2], acc3 = bv[3];
#pragma unroll
    for (int c = 0; c < 7; ++c) {
      const uint4* wp = Wl + (c * 4 + q) * 64 + n;
      union { uint4 u; bf16x8 v; } a0, a1, a2, a3;
      a0.u = wp[0];
      a1.u = wp[16];
      a2.u = wp[32];
      a3.u = wp[48];
      acc0 = __builtin_amdgcn_mfma_f32_16x16x32_bf16(a0.v, frag[c].v, acc0, 0, 0, 0);
      acc1 = __builtin_amdgcn_mfma_f32_16x16x32_bf16(a1.v, frag[c].v, acc1, 0, 0, 0);
      acc2 = __builtin_amdgcn_mfma_f32_16x16x32_bf16(a2.v, frag[c].v, acc2, 0, 0, 0);
      acc3 = __builtin_amdgcn_mfma_f32_16x16x32_bf16(a3.v, frag[c].v, acc3, 0, 0, 0);
    }

    // store: o = og*16 + q*4 + r, e = e0 + n
    {
      const int b = t / TPB;
      const int e0 = (t - b * TPB) * 16;
      float* ob = out + ((size_t)(b * C_OUT + q * 4) * E_DIM + e0 + n);
#pragma unroll
      for (int r = 0; r < 4; ++r) {
        ob[(size_t)(0 * 16 + r) * E_DIM] = acc0[r];
        ob[(size_t)(1 * 16 + r) * E_DIM] = acc1[r];
        ob[(size_t)(2 * 16 + r) * E_DIM] = acc2[r];
        ob[(size_t)(3 * 16 + r) * E_DIM] = acc3[r];
      }
    }

    if (!has) break;
    t = t1;
    t1 = t2;
#pragma unroll
    for (int s = 0; s < 5; ++s) cur[s] = nxt[s];
  }
}

// ============================================================================
// Fallback path (identical to previous best 3-kernel version) — used only if
// the cooperative launch is rejected (e.g. capture-unsupported).
// ============================================================================
__global__ __launch_bounds__(256) void xpose_kernel(const float* __restrict__ x,
                                                    u32* __restrict__ xT) {
  __shared__ u32 T[256 * 17];
  const int b = blockIdx.y;
  const int e0 = blockIdx.x * 256;
  const int t = threadIdx.x;
  const int nrows = min(256, E_DIM - e0);
  const float* xb = x + (size_t)b * 32 * E_DIM + e0;
  if (t < nrows) {
#pragma unroll
    for (int u = 0; u < 16; ++u) {
      const float lo = xb[(size_t)(2 * u) * E_DIM + t];
      const float hi = xb[(size_t)(2 * u + 1) * E_DIM + t];
      T[t * 17 + u] = pack_bf2(lo, hi);
    }
  }
  __syncthreads();
  const int total = nrows * 16;
  u32* dst = xT + ((size_t)b * E_DIM + e0) * 16;
#pragma unroll
  for (int k = 0; k < 16; ++k) {
    const int g = t + k * 256;
    if (g < total) dst[g] = T[(g >> 4) * 17 + (g & 15)];
  }
}

__global__ __launch_bounds__(256) void prep_w(const float* __restrict__ W,
                                              u32* __restrict__ Wa2) {
  const int p = blockIdx.x * 256 + threadIdx.x;
  if (p >= 7168) return;
  const int r = p & 3;
  const int o = (p >> 2) & 63;
  const int q = (p >> 8) & 3;
  const int s = p >> 10;
  const int kk = s < 3 ? s : s - 2;
  const int c0 = q * 8 + 2 * r;
  const float w0 = W[(o * 32 + c0) * 5 + kk];
  const float w1 = W[(o * 32 + c0 + 1) * 5 + kk];
  Wa2[p] = pack_bf2(w0, w1);
}

__global__ __launch_bounds__(256) void mesh_main(const u32* __restrict__ xT,
                                                 const int* __restrict__ Gi,
                                                 const u32* __restrict__ Wa2,
                                                 const float* __restrict__ bias,
                                                 float* __restrict__ out) {
  __shared__ uint4 Wl[WLDS_U4];
  {
    const uint4* src = (const uint4*)Wa2;
#pragma unroll
    for (int k = 0; k < 7; ++k) Wl[threadIdx.x + k * 256] = src[threadIdx.x + k * 256];
  }
  __syncthreads();

  const int l = threadIdx.x & 63;
  const int wv = threadIdx.x >> 6;
  const int n = l & 15;
  const int q = l >> 4;
  const int NW = NBLK * 4;

  f32x4 bv[4];
#pragma unroll
  for (int og = 0; og < 4; ++og) bv[og] = *(const f32x4*)(bias + og * 16 + q * 4);

  const uint4* xb4 = (const uint4*)xT;
  int t = blockIdx.x * 4 + wv;

  int gcur[5], gnext[5];
  {
    const int b = t / TPB;
    const int e = (t - b * TPB) * 16 + n;
    const int* gp = Gi + (b * E_DIM + e) * 5;
#pragma unroll
    for (int s = 0; s < 5; ++s) gcur[s] = b * E_DIM + gp[s];
  }
  uint4 cur[5];
#pragma unroll
  for (int s = 0; s < 5; ++s) cur[s] = xb4[(size_t)gcur[s] * 4 + q];

  int t1 = t + NW;
  if (t1 < NT) {
    const int b = t1 / TPB;
    const int e = (t1 - b * TPB) * 16 + n;
    const int* gp = Gi + (b * E_DIM + e) * 5;
#pragma unroll
    for (int s = 0; s < 5; ++s) gnext[s] = b * E_DIM + gp[s];
  }

  for (;;) {
    const bool has = t1 < NT;
    uint4 nxt[5];
    if (has) {
#pragma unroll
      for (int s = 0; s < 5; ++s) nxt[s] = xb4[(size_t)gnext[s] * 4 + q];
    }
    const int t2 = t1 + NW;
    if (t2 < NT) {
      const int b = t2 / TPB;
      const int e = (t2 - b * TPB) * 16 + n;
      const int* gp = Gi + (b * E_DIM + e) * 5;
#pragma unroll
      for (int s = 0; s < 5; ++s) gnext[s] = b * E_DIM + gp[s];
    }

    union { uint4 u; bf16x8 v; } frag[7];
#pragma unroll
    for (int s = 0; s < 5; ++s) frag[s].u = cur[s];
    frag[5].u = absdiff_vec(cur[1], cur[3]);
    frag[6].u = absdiff_vec(cur[2], cur[4]);

    f32x4 acc0 = bv[0], acc1 = bv[1], acc2 = bv[2], acc3 = bv[3];
#pragma unroll
    for (int c = 0; c < 7; ++c) {
      const uint4* wp = Wl + (c * 4 + q) * 64 + n;
      union { uint4 u; bf16x8 v; } a0, a1, a2, a3;
      a0.u = wp[0];
      a1.u = wp[16];
      a2.u = wp[32];
      a3.u = wp[48];
      acc0 = __builtin_amdgcn_mfma_f32_16x16x32_bf16(a0.v, frag[c].v, acc0, 0, 0, 0);
      acc1 = __builtin_amdgcn_mfma_f32_16x16x32_bf16(a1.v, frag[c].v, acc1, 0, 0, 0);
      acc2 = __builtin_amdgcn_mfma_f32_16x16x32_bf16(a2.v, frag[c].v, acc2, 0, 0, 0);
      acc3 = __builtin_amdgcn_mfma_f32_16x16x32_bf16(a3.v, frag[c].v, acc3, 0, 0, 0);
    }

    {
      const int b = t / TPB;
      const int e0 = (t - b * TPB) * 16;
      float* ob = out + ((size_t)(b * C_OUT + q * 4) * E_DIM + e0 + n);
#pragma unroll
      for (int r = 0; r < 4; ++r) {
        ob[(size_t)(0 * 16 + r) * E_DIM] = acc0[r];
        ob[(size_t)(1 * 16 + r) * E_DIM] = acc1[r];
        ob[(size_t)(2 * 16 + r) * E_DIM] = acc2[r];
        ob[(size_t)(3 * 16 + r) * E_DIM] = acc3[r];
      }
    }

    if (!has) break;
    t = t1;
    t1 = t2;
#pragma unroll
    for (int s = 0; s < 5; ++s) cur[s] = nxt[s];
  }
}

extern "C" void kernel_launch(void* const* d_in, const int* in_sizes, int n_in,
                              void* d_out, int out_size, void* d_ws, size_t ws_size,
                              hipStream_t stream) {
  const float* x    = (const float*)d_in[0];
  const int*   Gi   = (const int*)d_in[1];
  const float* W    = (const float*)d_in[2];
  const float* bias = (const float*)d_in[3];
  float* out = (float*)d_out;

  // workspace: xT packed-bf16 rows (B*E*16 u32 = 51.2 MB) [+ Wa2 in fallback]
  u32* xT = (u32*)d_ws;

  // occupancy-derived cooperative grid: guaranteed co-resident regardless of
  // final VGPR count (LDS 28 KB -> expect 5 blocks/CU -> 1280 blocks)
  static int maxb = -2;
  if (maxb == -2) {
    int mb = 0;
    if (hipOccupancyMaxActiveBlocksPerMultiprocessor(&mb, fused_mesh, 256, 0) != hipSuccess)
      mb = 0;
    maxb = mb;
  }

  bool done = false;
  if (maxb >= 1) {
    int nblk = maxb * 256;
    if (nblk > NBLK) nblk = NBLK;
    const float* xa = x; const int* ga = Gi; const float* wa = W;
    const float* ba = bias; u32* xta = xT; float* oa = out; int nb = nblk;
    void* args[] = {&xa, &ga, &wa, &ba, &xta, &oa, &nb};
    hipError_t err = hipLaunchCooperativeKernel((const void*)fused_mesh,
                                                dim3(nblk), dim3(256), args, 0, stream);
    if (err == hipSuccess) {
      done = true;
    } else {
      (void)hipGetLastError();  // clear sticky error, use fallback path
    }
  }

  if (!done) {
    u32* Wa2 = xT + (size_t)B_DIM * E_DIM * 16;
    dim3 gx((E_DIM + 255) / 256, B_DIM);
    xpose_kernel<<<gx, 256, 0, stream>>>(x, xT);
    prep_w<<<28, 256, 0, stream>>>(W, Wa2);
    mesh_main<<<NBLK, 256, 0, stream>>>(xT, Gi, Wa2, bias, out);
  }
}